// Round 3
// baseline (253.056 us; speedup 1.0000x reference)
//
#include <hip/hip_runtime.h>

// PyramidROIAlign: B=2, N=1000, C=256, pool 7x7, f32.
// One 64-lane wave per (box, py) pool row: 7 cells per wave.
// Lane handles channels 4l..4l+3 (float4). Corner columns shared between
// adjacent cells are reused in registers (wave-uniform branches — all lanes
// of a wave share the same box, so no divergence).
// Output stores are nontemporal: 100 MB streaming write would otherwise
// thrash the 32 MB aggregate L2 that the scattered corner reads rely on.

#define POOL 7
#define CCH 256

// native clang vector — __builtin_nontemporal_store requires this, HIP's
// float4 (HIP_vector_type class) is rejected.
typedef float f4 __attribute__((ext_vector_type(4)));

__global__ __launch_bounds__(256) void roi_align_row_kernel(
    const float* __restrict__ boxes,   // [B*N, 4] y1,x1,y2,x2
    const float* __restrict__ ish,     // [2]
    const float* __restrict__ P2,
    const float* __restrict__ P3,
    const float* __restrict__ P4,
    const float* __restrict__ P5,
    float* __restrict__ out,           // [B*N, 7, 7, C]
    int n_rows, int N)
{
    int row = blockIdx.x * 4 + (threadIdx.x >> 6);
    if (row >= n_rows) return;
    int lane = threadIdx.x & 63;
    int c = lane * 4;

    int py = row % POOL;
    int n  = row / POOL;         // flat box index in [0, B*N)
    int b  = n / N;              // batch index

    float y1 = boxes[n * 4 + 0];
    float x1 = boxes[n * 4 + 1];
    float y2 = boxes[n * 4 + 2];
    float x2 = boxes[n * 4 + 3];
    float h = y2 - y1;
    float w = x2 - x1;

    // compute_roi_level — same expression order as reference (rintf = np.round).
    float area = ish[0] * ish[1];
    float lvl  = log2f(sqrtf(h * w) / (224.0f / sqrtf(area)));
    float Lf   = fminf(5.0f, fmaxf(2.0f, 4.0f + rintf(lvl)));
    int   L    = (int)Lf;

    const float* fmap;
    int H;
    if (L == 2)      { fmap = P2; H = 256; }
    else if (L == 3) { fmap = P3; H = 128; }
    else if (L == 4) { fmap = P4; H = 64;  }
    else             { fmap = P5; H = 32;  }
    int W = H;

    // y sampling for this pool row (constant across the 7 cells)
    float gy   = (float)py * (1.0f / (POOL - 1));
    float in_y = (y1 + h * gy) * (float)(H - 1);
    float y0f  = floorf(in_y);
    float wy   = in_y - y0f;
    int y0  = min(max((int)y0f, 0), H - 1);
    int y1i = min(y0 + 1, H - 1);

    size_t base = (size_t)b * H * W * CCH + c;
    const float* rt = fmap + base + (size_t)y0  * W * CCH;  // top row, this lane's channels
    const float* rb = fmap + base + (size_t)y1i * W * CCH;  // bottom row

    float* orow = out + ((size_t)n * (POOL * POOL) + (size_t)py * POOL) * CCH + c;

    int px0 = -100, px1 = -100;  // previous cell's x0, x1i
    f4 tl, tr, bl, br;

    #pragma unroll
    for (int px = 0; px < POOL; ++px) {
        float gx   = (float)px * (1.0f / (POOL - 1));
        float in_x = (x1 + w * gx) * (float)(W - 1);
        float x0f  = floorf(in_x);
        float wx   = in_x - x0f;
        int x0  = min(max((int)x0f, 0), W - 1);
        int x1i = min(x0 + 1, W - 1);

        if (x0 == px0) {
            // same interval as previous cell — all 4 corners already in regs
        } else if (x0 == px1) {
            // shifted by one column — right corners become left corners
            tl = tr; bl = br;
            if (x1i != x0) {
                tr = *(const f4*)(rt + (size_t)x1i * CCH);
                br = *(const f4*)(rb + (size_t)x1i * CCH);
            } else { tr = tl; br = bl; }
        } else {
            tl = *(const f4*)(rt + (size_t)x0 * CCH);
            bl = *(const f4*)(rb + (size_t)x0 * CCH);
            if (x1i != x0) {
                tr = *(const f4*)(rt + (size_t)x1i * CCH);
                br = *(const f4*)(rb + (size_t)x1i * CCH);
            } else { tr = tl; br = bl; }
        }
        px0 = x0; px1 = x1i;

        f4 top = tl + (tr - tl) * wx;
        f4 bot = bl + (br - bl) * wx;
        f4 o   = top + (bot - top) * wy;

        __builtin_nontemporal_store(o, (f4*)(orow + (size_t)px * CCH));
    }
}

extern "C" void kernel_launch(void* const* d_in, const int* in_sizes, int n_in,
                              void* d_out, int out_size, void* d_ws, size_t ws_size,
                              hipStream_t stream)
{
    const float* boxes = (const float*)d_in[0];
    const float* ish   = (const float*)d_in[1];
    const float* P2    = (const float*)d_in[2];
    const float* P3    = (const float*)d_in[3];
    const float* P4    = (const float*)d_in[4];
    const float* P5    = (const float*)d_in[5];
    float* out = (float*)d_out;

    int total_boxes = in_sizes[0] / 4;                  // B*N = 2000
    int B = in_sizes[2] / (256 * 256 * CCH);            // P2 is [B,256,256,C]
    int N = total_boxes / B;
    int n_rows = total_boxes * POOL;                    // 14000 (box, py) rows

    int blocks = (n_rows + 3) / 4;                      // 4 waves (rows) per block
    roi_align_row_kernel<<<blocks, 256, 0, stream>>>(boxes, ish, P2, P3, P4, P5,
                                                     out, n_rows, N);
}